// Round 4
// baseline (359.213 us; speedup 1.0000x reference)
//
#include <hip/hip_runtime.h>
#include <stdint.h>

// graphConv: out[b] = (sum_k W_k S^k) @ X_b ; B=128, N=1024, D=64, K=8
//
// Tree (split-bf16 3-term GEMMs, fp32 atomic split-K partials):
//   L1: P_S2=S*S ; P_Tj=Wj*S (j=1,3,5,7)                 [5 jobs x KSPLIT=4]
//   combL1: S2=split(P_S2) rm+cm ; U1=split(P_T3+W2) ; U3=split(P_T7+W6)
//           P_V0 := P_T1+W0 (=U0, fp32) ; P_V1 := P_T5+W4 (=U2, fp32)
//   L2: P_S4+=S2*S2 ; P_V0+=U1*S2 ; P_V1+=U3*S2          [3 jobs x KSPLIT=4]
//   combL2: S4=split(P_S4) cm ; V1=split(P_V1) rm
//   L3: P_V0 += V1*S4   (P_V0 becomes A)                 [1 job x KSPLIT=8]
//   combL3: A_hi = bf16(P_V0)
//   apply: out' = A @ XT  (plain bf16, 64x128 tiles, XCD-L2-swizzled grid)
//
// Chain kernel: 128x128 tile, BK=32, 32 KB LDS (5-block LDS cap; ~3 by VGPR),
// rotate-swizzled 64B LDS rows (2-way banks = free), global_load_lds w=16.

#define NN 1024
#define NBATCH 128
#define DDIM 64

typedef float floatx4 __attribute__((ext_vector_type(4)));
typedef __bf16 bf16x8 __attribute__((ext_vector_type(8)));
typedef unsigned short u16;

__device__ __forceinline__ u16 f2bf(float f) {
  union { float f; uint32_t u; } v; v.f = f;
  uint32_t u = v.u;
  return (u16)((u + 0x7fffu + ((u >> 16) & 1u)) >> 16);  // RNE
}
__device__ __forceinline__ float bf2f(u16 h) {
  union { float f; uint32_t u; } v; v.u = ((uint32_t)h) << 16;
  return v.f;
}

__device__ __forceinline__ void gll16(const void* g, void* l) {
  __builtin_amdgcn_global_load_lds(
      (const __attribute__((address_space(1))) void*)g,
      (__attribute__((address_space(3))) void*)l, 16, 0, 0);
}

// ---- BK=32 stager: ROWS x 32 u16, 64B LDS rows, slot c holds logical chunk
// (c - (row>>1))&3. Readers use slot (q + (row>>1))&3. 2-way banks (free).
template <int ROWS>
__device__ __forceinline__ void stage32(const u16* __restrict__ g, u16* lds,
                                        int wave, int lane) {
  const int rr = lane >> 2, c = lane & 3;
#pragma unroll
  for (int i = 0; i < ROWS / 64; ++i) {
    const int rb = wave * (ROWS / 4) + i * 16;
    const int row = rb + rr;
    const int q = (c - (row >> 1)) & 3;
    gll16(g + (size_t)row * NN + q * 8, lds + rb * 32);
  }
}

// ---- BK=64 stager (apply): ROWS x 64 u16, 128B rows, (c^r) chunk swizzle.
template <int ROWS>
__device__ __forceinline__ void stage64(const u16* __restrict__ g, u16* lds,
                                        int wave, int lane) {
  const int r = lane >> 3, c = lane & 7;
  const int sw = (c ^ r) * 8;
#pragma unroll
  for (int i = 0; i < ROWS / 32; ++i) {
    const int rb = wave * (ROWS / 4) + i * 8;
    gll16(g + (size_t)(rb + r) * NN + sw, lds + rb * 64);
  }
}

// ---------------- split fp32 [+fp32] -> bf16 hi/lo, rm and/or cm -----------
struct SplitJob {
  const float* src; const float* add;   // add may be null
  u16* rmHi; u16* rmLo;                 // rmHi/rmLo may be null
  u16* cmHi; u16* cmLo;                 // may be null
};
struct SplitJobs { SplitJob j[5]; };

__global__ __launch_bounds__(256) void split_kernel(SplitJobs jobs) {
  SplitJob jb = jobs.j[blockIdx.z];
  int idx4 = blockIdx.x * 256 + threadIdx.x;
  int e = idx4 * 4;
  int row = e >> 10;
  int col = e & (NN - 1);
  float4 f = ((const float4*)jb.src)[idx4];
  float fv[4] = {f.x, f.y, f.z, f.w};
  if (jb.add) {
    float4 a = ((const float4*)jb.add)[idx4];
    fv[0] += a.x; fv[1] += a.y; fv[2] += a.z; fv[3] += a.w;
  }
  u16 hi[4], lo[4];
#pragma unroll
  for (int i = 0; i < 4; ++i) {
    hi[i] = f2bf(fv[i]);
    lo[i] = f2bf(fv[i] - bf2f(hi[i]));
  }
  if (jb.rmHi) {
    uint2 ph;
    ph.x = (uint32_t)hi[0] | ((uint32_t)hi[1] << 16);
    ph.y = (uint32_t)hi[2] | ((uint32_t)hi[3] << 16);
    *(uint2*)&jb.rmHi[e] = ph;
    if (jb.rmLo) {
      uint2 pl;
      pl.x = (uint32_t)lo[0] | ((uint32_t)lo[1] << 16);
      pl.y = (uint32_t)lo[2] | ((uint32_t)lo[3] << 16);
      *(uint2*)&jb.rmLo[e] = pl;
    }
  }
  if (jb.cmHi) {
#pragma unroll
    for (int i = 0; i < 4; ++i) {
      jb.cmHi[(size_t)(col + i) * NN + row] = hi[i];
      jb.cmLo[(size_t)(col + i) * NN + row] = lo[i];
    }
  }
}

// ---------------- fp32 dst += fp32 src (batched) ---------------------------
struct FaddJob { float* dst; const float* src; };
struct FaddJobs { FaddJob j[2]; };

__global__ __launch_bounds__(256) void fadd_kernel(FaddJobs jobs) {
  FaddJob jb = jobs.j[blockIdx.z];
  int i4 = blockIdx.x * 256 + threadIdx.x;
  float4 d = ((const float4*)jb.dst)[i4];
  float4 s = ((const float4*)jb.src)[i4];
  d.x += s.x; d.y += s.y; d.z += s.z; d.w += s.w;
  ((float4*)jb.dst)[i4] = d;
}

// ---------------- transpose X [B,K,D] fp32 -> XT [B*D, K] bf16 -------------
__global__ __launch_bounds__(256) void transpose_x(const float* __restrict__ X,
                                                   u16* __restrict__ XT) {
  __shared__ u16 T[64][72];
  const int k0 = blockIdx.x * 64;
  const int b = blockIdx.y;
  const int t = threadIdx.x;
#pragma unroll
  for (int it = 0; it < 4; ++it) {
    int kr = (t >> 4) + it * 16;
    int d4 = (t & 15) * 4;
    float4 f = *(const float4*)&X[((size_t)b * NN + k0 + kr) * DDIM + d4];
    T[d4 + 0][kr] = f2bf(f.x);
    T[d4 + 1][kr] = f2bf(f.y);
    T[d4 + 2][kr] = f2bf(f.z);
    T[d4 + 3][kr] = f2bf(f.w);
  }
  __syncthreads();
#pragma unroll
  for (int it = 0; it < 2; ++it) {
    int d = (t >> 3) + it * 32;
    int kc = (t & 7) * 8;
    *(uint4*)&XT[((size_t)b * DDIM + d) * NN + k0 + kc] = *(uint4*)&T[d][kc];
  }
}

// ---------------- chain GEMM: dst += A*B, split 3-term, atomic split-K -----
struct AtomJob {
  const u16* Ah; const u16* Al;   // A row-major
  const u16* Bh; const u16* Bl;   // B col-major (B^T rows = n)
  float* dst;                     // fp32, atomically accumulated
};
struct AtomJobs { AtomJob j[5]; };

template <int KSPLIT>
__global__ __launch_bounds__(256, 3) void chain_atomic(AtomJobs jobs) {
  const AtomJob jb = jobs.j[blockIdx.z / KSPLIT];
  const int chunk = blockIdx.z % KSPLIT;
  constexpr int KTPB = 32 / KSPLIT;
  __shared__ u16 AH[4096], AL[4096], BH[4096], BL[4096];  // 32 KB
  const int t = threadIdx.x, wave = t >> 6, lane = t & 63;
  const int wm = wave >> 1, wn = wave & 1;
  const int lm = lane & 15, q = lane >> 4;
  const int bm = blockIdx.x * 128, bn = blockIdx.y * 128;
  floatx4 acc[4][4] = {};

  int aoff[4], boff[4];
#pragma unroll
  for (int i = 0; i < 4; ++i) {
    int ra = wm * 64 + i * 16 + lm;
    aoff[i] = ra * 32 + (((q + (ra >> 1)) & 3) * 8);
    int rb = wn * 64 + i * 16 + lm;
    boff[i] = rb * 32 + (((q + (rb >> 1)) & 3) * 8);
  }

  for (int kk = 0; kk < KTPB; ++kk) {
    const int kb = (chunk * KTPB + kk) * 32;
    __syncthreads();
    stage32<128>(jb.Ah + (size_t)bm * NN + kb, AH, wave, lane);
    stage32<128>(jb.Al + (size_t)bm * NN + kb, AL, wave, lane);
    stage32<128>(jb.Bh + (size_t)bn * NN + kb, BH, wave, lane);
    stage32<128>(jb.Bl + (size_t)bn * NN + kb, BL, wave, lane);
    __syncthreads();
    bf16x8 bh[4], bl[4];
#pragma unroll
    for (int ni = 0; ni < 4; ++ni) {
      bh[ni] = *(const bf16x8*)&BH[boff[ni]];
      bl[ni] = *(const bf16x8*)&BL[boff[ni]];
    }
#pragma unroll
    for (int mi = 0; mi < 4; ++mi) {
      bf16x8 ah = *(const bf16x8*)&AH[aoff[mi]];
      bf16x8 al = *(const bf16x8*)&AL[aoff[mi]];
#pragma unroll
      for (int ni = 0; ni < 4; ++ni) {
        acc[mi][ni] = __builtin_amdgcn_mfma_f32_16x16x32_bf16(ah, bh[ni], acc[mi][ni], 0, 0, 0);
        acc[mi][ni] = __builtin_amdgcn_mfma_f32_16x16x32_bf16(ah, bl[ni], acc[mi][ni], 0, 0, 0);
        acc[mi][ni] = __builtin_amdgcn_mfma_f32_16x16x32_bf16(al, bh[ni], acc[mi][ni], 0, 0, 0);
      }
    }
  }

#pragma unroll
  for (int mi = 0; mi < 4; ++mi)
#pragma unroll
    for (int ni = 0; ni < 4; ++ni)
#pragma unroll
      for (int r = 0; r < 4; ++r) {
        int row = bm + wm * 64 + mi * 16 + q * 4 + r;
        int col = bn + wn * 64 + ni * 16 + lm;
        atomicAdd(&jb.dst[(size_t)row * NN + col], acc[mi][ni][r]);
      }
}

// ---------------- apply: out'[n, bd] = A @ XT^T (plain bf16) ---------------
// grid.x = bd-tile (64), grid.y = n-tile (16): the 16 y-blocks per x share an
// XT slice and land on one XCD (id%8 = x%8) -> XT served from that XCD's L2.
__global__ __launch_bounds__(256, 4) void apply_gemm(const u16* __restrict__ A,
                                                     const u16* __restrict__ XT,
                                                     float* __restrict__ out) {
  __shared__ u16 Als[4096], Bt[8192];  // 8 KB + 16 KB
  const int t = threadIdx.x, wave = t >> 6, lane = t & 63;
  const int wm = wave >> 1, wn = wave & 1;
  const int lm = lane & 15, q = lane >> 4;
  const int bm = blockIdx.y * 64, bn = blockIdx.x * 128;
  floatx4 acc[2][4] = {};

  for (int kt = 0; kt < 16; ++kt) {
    __syncthreads();
    stage64<64>(A + (size_t)bm * NN + kt * 64, Als, wave, lane);
    stage64<128>(XT + (size_t)bn * NN + kt * 64, Bt, wave, lane);
    __syncthreads();
#pragma unroll
    for (int ks = 0; ks < 2; ++ks) {
      const int st = ((ks * 4 + q) ^ (lm & 7)) * 8;
      bf16x8 bb[4];
#pragma unroll
      for (int ni = 0; ni < 4; ++ni)
        bb[ni] = *(const bf16x8*)&Bt[(wn * 64 + ni * 16 + lm) * 64 + st];
#pragma unroll
      for (int mi = 0; mi < 2; ++mi) {
        bf16x8 a = *(const bf16x8*)&Als[(wm * 32 + mi * 16 + lm) * 64 + st];
#pragma unroll
        for (int ni = 0; ni < 4; ++ni)
          acc[mi][ni] = __builtin_amdgcn_mfma_f32_16x16x32_bf16(a, bb[ni], acc[mi][ni], 0, 0, 0);
      }
    }
  }

#pragma unroll
  for (int mi = 0; mi < 2; ++mi)
#pragma unroll
    for (int ni = 0; ni < 4; ++ni)
#pragma unroll
      for (int r = 0; r < 4; ++r) {
        int row = bm + wm * 32 + mi * 16 + q * 4 + r;
        int col = bn + wn * 64 + ni * 16 + lm;
        int b = col >> 6, d = col & 63;
        out[((size_t)b * NN + row) * DDIM + d] = acc[mi][ni][r];
      }
}

extern "C" void kernel_launch(void* const* d_in, const int* in_sizes, int n_in,
                              void* d_out, int out_size, void* d_ws, size_t ws_size,
                              hipStream_t stream) {
  const float* nodes  = (const float*)d_in[0];  // [128,1024,64]
  const float* weight = (const float*)d_in[1];  // [8,1024,1024]
  const float* gs     = (const float*)d_in[2];  // [1024,1024]
  float* out = (float*)d_out;
  u16* ws = (u16*)d_ws;
  const size_t MB = (size_t)NN * NN;
  auto buf  = [&](int i) -> u16*  { return ws + (size_t)i * MB; };
  auto fbuf = [&](int i) -> float* { return (float*)(ws + (size_t)i * MB); };
  // 2MB slots: 0,1 S rm hi/lo | 2,3 S cm hi/lo | 4..11 W1,3,5,7 hi/lo
  // 12,13 P_S2->P_S4 | 14,15 P_T1->P_V0->A | 16,17 P_T3 (->A_hi slot 16)
  // 18,19 P_T5->P_V1 | 20,21 P_T7 | 22,23 S2 rm | 24,25 S2 cm
  // 26,27 U1 | 28,29 U3 | after L2: 0,1 S4 cm ; 2,3 V1 | XT overlays 4..11
  // Peak 60 MB.

  // phase 0: split S (rm+cm) and odd W's
  SplitJobs s0{};
  s0.j[0] = { gs,              nullptr, buf(0),  buf(1),  buf(2), buf(3) };
  s0.j[1] = { weight + 1 * MB, nullptr, buf(4),  buf(5),  nullptr, nullptr };
  s0.j[2] = { weight + 3 * MB, nullptr, buf(6),  buf(7),  nullptr, nullptr };
  s0.j[3] = { weight + 5 * MB, nullptr, buf(8),  buf(9),  nullptr, nullptr };
  s0.j[4] = { weight + 7 * MB, nullptr, buf(10), buf(11), nullptr, nullptr };
  split_kernel<<<dim3(NN * NN / 1024, 1, 5), 256, 0, stream>>>(s0);

  hipMemsetAsync(buf(12), 0, 10 * MB * sizeof(u16), stream);  // P_S2,P_T1..7

  // L1: P_S2 += S*S ; P_Tj += Wj*S
  AtomJobs a1{};
  a1.j[0] = { buf(0),  buf(1),  buf(2), buf(3), fbuf(12) };
  a1.j[1] = { buf(4),  buf(5),  buf(2), buf(3), fbuf(14) };
  a1.j[2] = { buf(6),  buf(7),  buf(2), buf(3), fbuf(16) };
  a1.j[3] = { buf(8),  buf(9),  buf(2), buf(3), fbuf(18) };
  a1.j[4] = { buf(10), buf(11), buf(2), buf(3), fbuf(20) };
  chain_atomic<4><<<dim3(8, 8, 20), 256, 0, stream>>>(a1);

  u16* XT = buf(4);  // W splits dead after L1
  transpose_x<<<dim3(16, NBATCH), 256, 0, stream>>>(nodes, XT);

  // combL1: S2 split rm+cm ; U1 = P_T3+W2 ; U3 = P_T7+W6 (split rm)
  SplitJobs s1{};
  s1.j[0] = { fbuf(12), nullptr,        buf(22), buf(23), buf(24), buf(25) };
  s1.j[1] = { fbuf(16), weight + 2 * MB, buf(26), buf(27), nullptr, nullptr };
  s1.j[2] = { fbuf(20), weight + 6 * MB, buf(28), buf(29), nullptr, nullptr };
  split_kernel<<<dim3(NN * NN / 1024, 1, 3), 256, 0, stream>>>(s1);

  // seeds: P_V0 = P_T1 + W0 ; P_V1 = P_T5 + W4
  FaddJobs f1{};
  f1.j[0] = { fbuf(14), weight + 0 * MB };
  f1.j[1] = { fbuf(18), weight + 4 * MB };
  fadd_kernel<<<dim3(NN * NN / 1024, 1, 2), 256, 0, stream>>>(f1);

  hipMemsetAsync(buf(12), 0, 2 * MB * sizeof(u16), stream);   // P_S4

  // L2: P_S4 += S2*S2 ; P_V0 += U1*S2 ; P_V1 += U3*S2
  AtomJobs a2{};
  a2.j[0] = { buf(22), buf(23), buf(24), buf(25), fbuf(12) };
  a2.j[1] = { buf(26), buf(27), buf(24), buf(25), fbuf(14) };
  a2.j[2] = { buf(28), buf(29), buf(24), buf(25), fbuf(18) };
  chain_atomic<4><<<dim3(8, 8, 12), 256, 0, stream>>>(a2);

  // combL2: S4 cm-only ; V1 split rm
  SplitJobs s2{};
  s2.j[0] = { fbuf(12), nullptr, nullptr, nullptr, buf(0), buf(1) };
  s2.j[1] = { fbuf(18), nullptr, buf(2),  buf(3),  nullptr, nullptr };
  split_kernel<<<dim3(NN * NN / 1024, 1, 2), 256, 0, stream>>>(s2);

  // L3: P_V0 += V1*S4  (P_V0 becomes A, fp32)
  AtomJobs a3{};
  a3.j[0] = { buf(2), buf(3), buf(0), buf(1), fbuf(14) };
  chain_atomic<8><<<dim3(8, 8, 8), 256, 0, stream>>>(a3);

  // combL3: A_hi = bf16(A)
  SplitJobs s3{};
  s3.j[0] = { fbuf(14), nullptr, buf(16), nullptr, nullptr, nullptr };
  split_kernel<<<dim3(NN * NN / 1024, 1, 1), 256, 0, stream>>>(s3);

  apply_gemm<<<dim3(64, 16), 256, 0, stream>>>(buf(16), XT, out);
}

// Round 5
// 200.021 us; speedup vs baseline: 1.7959x; 1.7959x over previous
//
#include <hip/hip_runtime.h>
#include <stdint.h>

// graphConv: out[b] = (sum_k W_k S^k) @ X_b ; B=128, N=1024, D=64, K=8
//
// All-fp16 tree (fp32 MFMA accumulate; fp16 unit roundoff 2^-11 -> est
// absmax ~0.02 vs threshold 0.295):
//   cvt: S (rm+cm), W1,W3,W5,W7 (rm) -> fp16
//   L1: S2 = S*S (rm+cm) ; U_j = W_{2j}(fp32 add) + W_{2j+1}*S  [5 jobs]
//   L2: S4 = S2*S2 (cm) ; V0 = U0 + U1*S2 ; V1 = U2 + U3*S2     [3 jobs]
//   L3: P = V1*S4, split-K=4 fp32 partials (non-atomic)         [1024 blk]
//   combine: A = V0 + sum P
//   apply: out[b] = A @ X_b  -- 128n x 64d x batch tiles, 1024 blocks;
//          grid.x=b so XCD(id%8)=b%8: XT slice fetched once, A L2-resident.
// GEMM: BK=64, XOR-swizzled 128B LDS rows (R2-verified conflict-free),
// global_load_lds width=16.

#define NN 1024
#define NBATCH 128
#define DDIM 64

typedef float floatx4 __attribute__((ext_vector_type(4)));
typedef _Float16 f16x8 __attribute__((ext_vector_type(8)));
typedef unsigned short u16;

__device__ __forceinline__ u16 f2h(float f) {
  union { _Float16 h; u16 u; } v; v.h = (_Float16)f; return v.u;
}
__device__ __forceinline__ float h2f(u16 u) {
  union { _Float16 h; u16 u; } v; v.u = u; return (float)v.h;
}

__device__ __forceinline__ void gll16(const void* g, void* l) {
  __builtin_amdgcn_global_load_lds(
      (const __attribute__((address_space(1))) void*)g,
      (__attribute__((address_space(3))) void*)l, 16, 0, 0);
}

// Stage ROWS x 64 u16 tile (row stride NN) into linear LDS, 16B chunks
// XOR-swizzled by row&7. Conflict-free on DMA write and ds_read_b128.
template <int ROWS>
__device__ __forceinline__ void stage64(const u16* __restrict__ g, u16* lds,
                                        int wave, int lane) {
  const int r = lane >> 3, c = lane & 7;
  const int sw = (c ^ r) * 8;
#pragma unroll
  for (int i = 0; i < ROWS / 32; ++i) {
    const int rb = wave * (ROWS / 4) + i * 8;
    gll16(g + (size_t)(rb + r) * NN + sw, lds + rb * 64);
  }
}

// ---------------- convert fp32 -> fp16, rm (+ optional cm) -----------------
struct CvtJob { const float* src; u16* rm; u16* cm; };
struct CvtJobs { CvtJob j[5]; };

__global__ __launch_bounds__(256) void cvt_kernel(CvtJobs jobs) {
  CvtJob jb = jobs.j[blockIdx.z];
  int idx4 = blockIdx.x * 256 + threadIdx.x;
  int e = idx4 * 4;
  int row = e >> 10, col = e & (NN - 1);
  float4 f = ((const float4*)jb.src)[idx4];
  u16 h[4] = { f2h(f.x), f2h(f.y), f2h(f.z), f2h(f.w) };
  uint2 p;
  p.x = (uint32_t)h[0] | ((uint32_t)h[1] << 16);
  p.y = (uint32_t)h[2] | ((uint32_t)h[3] << 16);
  *(uint2*)&jb.rm[e] = p;
  if (jb.cm) {
#pragma unroll
    for (int i = 0; i < 4; ++i) jb.cm[(size_t)(col + i) * NN + row] = h[i];
  }
}

// ---------------- transpose X [B,K,D] fp32 -> XT [B*D, K] fp16 -------------
__global__ __launch_bounds__(256) void transpose_x(const float* __restrict__ X,
                                                   u16* __restrict__ XT) {
  __shared__ u16 T[64][72];
  const int k0 = blockIdx.x * 64;
  const int b = blockIdx.y;
  const int t = threadIdx.x;
#pragma unroll
  for (int it = 0; it < 4; ++it) {
    int kr = (t >> 4) + it * 16;
    int d4 = (t & 15) * 4;
    float4 f = *(const float4*)&X[((size_t)b * NN + k0 + kr) * DDIM + d4];
    T[d4 + 0][kr] = f2h(f.x);
    T[d4 + 1][kr] = f2h(f.y);
    T[d4 + 2][kr] = f2h(f.z);
    T[d4 + 3][kr] = f2h(f.w);
  }
  __syncthreads();
#pragma unroll
  for (int it = 0; it < 2; ++it) {
    int d = (t >> 3) + it * 32;
    int kc = (t & 7) * 8;
    *(uint4*)&XT[((size_t)b * DDIM + d) * NN + k0 + kc] = *(uint4*)&T[d][kc];
  }
}

// ---------------- fp16 GEMM: out = [add +] A*B ----------------------------
struct GemmJob {
  const u16* A;        // fp16 row-major MxK
  const u16* B;        // fp16 col-major: (k,n) at [n*NN+k]
  const float* addF;   // optional fp32 additive (row-major)
  const u16* addH;     // optional fp16 additive (row-major)
  u16* outRm;          // optional fp16 row-major out
  u16* outCm;          // optional fp16 col-major out
  float* outP;         // split-K fp32 partials (KSPLIT>1 path)
};
struct GemmJobs { GemmJob j[5]; };

template <int BM, int BN, int KSPLIT>
__global__ __launch_bounds__(256) void gemm_f16(GemmJobs jobs) {
  const GemmJob jb = jobs.j[blockIdx.z / KSPLIT];
  const int chunk = blockIdx.z % KSPLIT;
  __shared__ u16 As[BM * 64], Bs[BN * 64];
  const int t = threadIdx.x, wave = t >> 6, lane = t & 63;
  const int wm = wave >> 1, wn = wave & 1;
  const int lm = lane & 15, q = lane >> 4;
  const int bm = blockIdx.x * BM, bn = blockIdx.y * BN;
  constexpr int MI = BM / 32, NI = BN / 32, KTPB = 16 / KSPLIT;
  floatx4 acc[MI][NI] = {};

  for (int kk = 0; kk < KTPB; ++kk) {
    const int kt = chunk * KTPB + kk;
    __syncthreads();
    stage64<BM>(jb.A + (size_t)bm * NN + kt * 64, As, wave, lane);
    stage64<BN>(jb.B + (size_t)bn * NN + kt * 64, Bs, wave, lane);
    __syncthreads();
#pragma unroll
    for (int ks = 0; ks < 2; ++ks) {
      const int st = ((ks * 4 + q) ^ (lm & 7)) * 8;
      f16x8 bf[NI];
#pragma unroll
      for (int ni = 0; ni < NI; ++ni)
        bf[ni] = *(const f16x8*)&Bs[(wn * (BN / 2) + ni * 16 + lm) * 64 + st];
#pragma unroll
      for (int mi = 0; mi < MI; ++mi) {
        f16x8 a = *(const f16x8*)&As[(wm * (BM / 2) + mi * 16 + lm) * 64 + st];
#pragma unroll
        for (int ni = 0; ni < NI; ++ni)
          acc[mi][ni] = __builtin_amdgcn_mfma_f32_16x16x32_f16(a, bf[ni], acc[mi][ni], 0, 0, 0);
      }
    }
  }

  if (KSPLIT > 1) {
    float* p = jb.outP + (size_t)chunk * NN * NN;
#pragma unroll
    for (int mi = 0; mi < MI; ++mi)
#pragma unroll
      for (int ni = 0; ni < NI; ++ni)
#pragma unroll
        for (int r = 0; r < 4; ++r) {
          int row = bm + wm * (BM / 2) + mi * 16 + q * 4 + r;
          int col = bn + wn * (BN / 2) + ni * 16 + lm;
          p[(size_t)row * NN + col] = acc[mi][ni][r];
        }
  } else {
#pragma unroll
    for (int mi = 0; mi < MI; ++mi)
#pragma unroll
      for (int ni = 0; ni < NI; ++ni)
#pragma unroll
        for (int r = 0; r < 4; ++r) {
          int row = bm + wm * (BM / 2) + mi * 16 + q * 4 + r;
          int col = bn + wn * (BN / 2) + ni * 16 + lm;
          size_t rm = (size_t)row * NN + col;
          float v = acc[mi][ni][r];
          if (jb.addF) v += jb.addF[rm];
          if (jb.addH) v += h2f(jb.addH[rm]);
          u16 h = f2h(v);
          if (jb.outRm) jb.outRm[rm] = h;
          if (jb.outCm) jb.outCm[(size_t)col * NN + row] = h;
        }
  }
}

// ---------------- combine: A = V0 + sum_z P ---------------------------------
__global__ __launch_bounds__(256) void combine_A(const float* __restrict__ parts,
                                                 const u16* __restrict__ v0,
                                                 u16* __restrict__ A) {
  int e = (blockIdx.x * 256 + threadIdx.x) * 4;
  float4 s = *(const float4*)&parts[e];
#pragma unroll
  for (int z = 1; z < 4; ++z) {
    float4 p = *(const float4*)&parts[(size_t)z * NN * NN + e];
    s.x += p.x; s.y += p.y; s.z += p.z; s.w += p.w;
  }
  uint2 h = *(const uint2*)&v0[e];
  uint2 o;
  o.x = (uint32_t)f2h(s.x + h2f((u16)h.x)) |
        ((uint32_t)f2h(s.y + h2f((u16)(h.x >> 16))) << 16);
  o.y = (uint32_t)f2h(s.z + h2f((u16)h.y)) |
        ((uint32_t)f2h(s.w + h2f((u16)(h.y >> 16))) << 16);
  *(uint2*)&A[e] = o;
}

// ---------------- apply: out[b][n][d] = A @ X_b ----------------------------
// Block = 128 n-rows x all 64 d x one b. grid(x=b,y=ntile): XCD = b%8, so
// each XT slice is fetched by one XCD; A (2 MB fp16) goes L2-resident.
__global__ __launch_bounds__(256) void apply_gemm(const u16* __restrict__ A,
                                                  const u16* __restrict__ XT,
                                                  float* __restrict__ out) {
  __shared__ u16 As[8192], Xs[4096];  // 16 KB + 8 KB
  const int t = threadIdx.x, wave = t >> 6, lane = t & 63;
  const int lm = lane & 15, q = lane >> 4;
  const int b = blockIdx.x, bm = blockIdx.y * 128;
  floatx4 acc[2][4] = {};

  for (int kt = 0; kt < 16; ++kt) {
    __syncthreads();
    stage64<128>(A + (size_t)bm * NN + kt * 64, As, wave, lane);
    stage64<64>(XT + (size_t)b * DDIM * NN + kt * 64, Xs, wave, lane);
    __syncthreads();
#pragma unroll
    for (int ks = 0; ks < 2; ++ks) {
      const int st = ((ks * 4 + q) ^ (lm & 7)) * 8;
      f16x8 x[4];
#pragma unroll
      for (int ni = 0; ni < 4; ++ni)
        x[ni] = *(const f16x8*)&Xs[(ni * 16 + lm) * 64 + st];
#pragma unroll
      for (int mi = 0; mi < 2; ++mi) {
        f16x8 a = *(const f16x8*)&As[(wave * 32 + mi * 16 + lm) * 64 + st];
#pragma unroll
        for (int ni = 0; ni < 4; ++ni)
          acc[mi][ni] = __builtin_amdgcn_mfma_f32_16x16x32_f16(a, x[ni], acc[mi][ni], 0, 0, 0);
      }
    }
  }

#pragma unroll
  for (int mi = 0; mi < 2; ++mi)
#pragma unroll
    for (int ni = 0; ni < 4; ++ni)
#pragma unroll
      for (int r = 0; r < 4; ++r) {
        int row = bm + wave * 32 + mi * 16 + q * 4 + r;
        int d = ni * 16 + lm;
        out[((size_t)b * NN + row) * DDIM + d] = acc[mi][ni][r];
      }
}

extern "C" void kernel_launch(void* const* d_in, const int* in_sizes, int n_in,
                              void* d_out, int out_size, void* d_ws, size_t ws_size,
                              hipStream_t stream) {
  const float* nodes  = (const float*)d_in[0];  // [128,1024,64]
  const float* weight = (const float*)d_in[1];  // [8,1024,1024]
  const float* gs     = (const float*)d_in[2];  // [1024,1024]
  float* out = (float*)d_out;
  u16* ws = (u16*)d_ws;
  const size_t MB = (size_t)NN * NN;
  auto buf = [&](int i) -> u16* { return ws + (size_t)i * MB; };
  // 2MB fp16 slots: 0 S rm | 1 S cm | 2..5 W1,3,5,7 rm | 6 S2 rm | 7 S2 cm
  // 8..11 U0..U3 | 12 S4 cm | 13 V0 | 14 V1 | 15 A | 16..23 XT (16 MB)
  // 24..31 L3 fp32 partials (16 MB). Total 64 MB.

  CvtJobs cv{};
  cv.j[0] = { gs,              buf(0), buf(1) };
  cv.j[1] = { weight + 1 * MB, buf(2), nullptr };
  cv.j[2] = { weight + 3 * MB, buf(3), nullptr };
  cv.j[3] = { weight + 5 * MB, buf(4), nullptr };
  cv.j[4] = { weight + 7 * MB, buf(5), nullptr };
  cvt_kernel<<<dim3(NN * NN / 1024, 1, 5), 256, 0, stream>>>(cv);

  // L1: S2 = S*S ; U_j = W_{2j} + W_{2j+1}*S
  GemmJobs g1{};
  g1.j[0] = { buf(0), buf(1), nullptr,         nullptr, buf(6),  buf(7),  nullptr };
  g1.j[1] = { buf(2), buf(1), weight + 0 * MB, nullptr, buf(8),  nullptr, nullptr };
  g1.j[2] = { buf(3), buf(1), weight + 2 * MB, nullptr, buf(9),  nullptr, nullptr };
  g1.j[3] = { buf(4), buf(1), weight + 4 * MB, nullptr, buf(10), nullptr, nullptr };
  g1.j[4] = { buf(5), buf(1), weight + 6 * MB, nullptr, buf(11), nullptr, nullptr };
  gemm_f16<64, 128, 1><<<dim3(16, 8, 5), 256, 0, stream>>>(g1);

  u16* XT = buf(16);
  transpose_x<<<dim3(16, NBATCH), 256, 0, stream>>>(nodes, XT);

  // L2: S4 = S2*S2 (cm) ; V0 = U0 + U1*S2 ; V1 = U2 + U3*S2
  GemmJobs g2{};
  g2.j[0] = { buf(6),  buf(7), nullptr, nullptr, nullptr, buf(12), nullptr };
  g2.j[1] = { buf(9),  buf(7), nullptr, buf(8),  buf(13), nullptr, nullptr };
  g2.j[2] = { buf(11), buf(7), nullptr, buf(10), buf(14), nullptr, nullptr };
  gemm_f16<64, 64, 1><<<dim3(16, 16, 3), 256, 0, stream>>>(g2);

  // L3: P = V1*S4, split-K=4 non-atomic partials
  float* parts = (float*)buf(24);
  GemmJobs g3{};
  g3.j[0] = { buf(14), buf(12), nullptr, nullptr, nullptr, nullptr, parts };
  gemm_f16<64, 64, 4><<<dim3(16, 16, 4), 256, 0, stream>>>(g3);

  // A = V0 + sum P
  combine_A<<<dim3(NN * NN / 1024), 256, 0, stream>>>(parts, buf(13), buf(15));

  apply_gemm<<<dim3(NBATCH, 8), 256, 0, stream>>>(buf(15), XT, out);
}